// Round 1
// baseline (2027.839 us; speedup 1.0000x reference)
//
#include <hip/hip_runtime.h>
#include <cstdint>
#include <cstddef>

// ---------------- constants ----------------
#define D_  384
#define H_  8
#define HS_ 48
#define L_  8
#define V_  32000
#define B_  32
#define T_  128
#define M_  4096   // B*T

typedef __bf16 bf16;
typedef __bf16 bf16x8 __attribute__((ext_vector_type(8)));
typedef float  floatx4 __attribute__((ext_vector_type(4)));

__device__ __forceinline__ unsigned short bfbits(float f) {
  union { bf16 b; unsigned short u; } cv; cv.b = (bf16)f; return cv.u;
}

__device__ __forceinline__ float waveReduceSum(float v) {
  #pragma unroll
  for (int off = 32; off > 0; off >>= 1) v += __shfl_xor(v, off, 64);
  return v;
}

// ---------------- embedding: x = tok_emb[idx] + pos_emb[t]; also bf16 copy ----------------
__global__ void embed_kernel(const int* __restrict__ idx, const float* __restrict__ tok,
                             const float* __restrict__ pos, float* __restrict__ x,
                             bf16* __restrict__ xb) {
  int e = blockIdx.x * 256 + threadIdx.x;       // 0 .. 4096*96-1
  int row = e / 96, c4 = (e % 96) * 4;
  int t = row & (T_ - 1);
  int tk = idx[row];
  const float4 tv = *(const float4*)(tok + (size_t)tk * D_ + c4);
  const float4 pv = *(const float4*)(pos + (size_t)t * D_ + c4);
  float4 o; o.x = tv.x + pv.x; o.y = tv.y + pv.y; o.z = tv.z + pv.z; o.w = tv.w + pv.w;
  *(float4*)(x + (size_t)row * D_ + c4) = o;
  uint2 u;
  u.x = (unsigned)bfbits(o.x) | ((unsigned)bfbits(o.y) << 16);
  u.y = (unsigned)bfbits(o.z) | ((unsigned)bfbits(o.w) << 16);
  *(uint2*)(xb + (size_t)row * D_ + c4) = u;
}

// ---------------- transpose+convert: W [K][N] f32 -> Wt [N][K] bf16 ----------------
__device__ __forceinline__ void transpose_tile(const float* __restrict__ src, bf16* __restrict__ dst,
                                               int K, int N, int k0, int n0) {
  __shared__ float tile[32][33];
  const int r = threadIdx.x >> 5, c = threadIdx.x & 31;
  #pragma unroll
  for (int i = 0; i < 4; i++)
    tile[r + 8*i][c] = src[(size_t)(k0 + r + 8*i) * N + n0 + c];
  __syncthreads();
  #pragma unroll
  for (int i = 0; i < 4; i++)
    dst[(size_t)(n0 + r + 8*i) * K + k0 + c] = (bf16)tile[c][r + 8*i];
}

__global__ void t_qkvo_kernel(const float* __restrict__ Wq, const float* __restrict__ Wk,
                              const float* __restrict__ Wv, const float* __restrict__ Wo,
                              bf16* __restrict__ dst) {
  const float* src = blockIdx.z == 0 ? Wq : blockIdx.z == 1 ? Wk : blockIdx.z == 2 ? Wv : Wo;
  transpose_tile(src, dst + (size_t)blockIdx.z * (D_ * D_), D_, D_, blockIdx.y * 32, blockIdx.x * 32);
}

__global__ void t_ffn_kernel(const float* __restrict__ W1, const float* __restrict__ W2,
                             bf16* __restrict__ w1t, bf16* __restrict__ w2t) {
  if (blockIdx.z == 0) {
    if (blockIdx.x >= 48 || blockIdx.y >= 12) return;
    transpose_tile(W1, w1t, D_, 4 * D_, blockIdx.y * 32, blockIdx.x * 32);
  } else {
    if (blockIdx.x >= 12 || blockIdx.y >= 48) return;
    transpose_tile(W2, w2t, 4 * D_, D_, blockIdx.y * 32, blockIdx.x * 32);
  }
}

__global__ void t_head_kernel(const float* __restrict__ lmW, bf16* __restrict__ dst) {
  transpose_tile(lmW, dst, D_, V_, blockIdx.y * 32, blockIdx.x * 32);
}

// ---------------- GEMM: C[M][N] = A[M][K](bf16) @ Bt[N][K]^T(bf16), fp32 acc ----------------
// 128x128 block tile, 4 waves 2x2, BK=32, mfma_f32_16x16x32_bf16.
// LDS rows padded to 56 bf16 (112B = 7*16B): 16B-aligned b128, 2-way bank aliasing (free).
template<bool BIAS, bool RESID, bool RELU, bool OUTBF>
__device__ __forceinline__ void gemm_core(
    const bf16* __restrict__ A, const bf16* __restrict__ Bt,
    const float* __restrict__ bias, const float* __restrict__ resid,
    void* __restrict__ Cout, int N, int K, int m0, int n0)
{
  __shared__ bf16 As[128][56];
  __shared__ bf16 Bs[128][56];
  const int tid  = threadIdx.x;
  const int lane = tid & 63;
  const int wave = tid >> 6;
  const int wr = wave >> 1, wc = wave & 1;
  const int lrow = lane & 15, quad = lane >> 4;

  floatx4 acc[4][4];
  #pragma unroll
  for (int i = 0; i < 4; i++)
    #pragma unroll
    for (int j = 0; j < 4; j++) acc[i][j] = floatx4{0.f, 0.f, 0.f, 0.f};

  const int r0 = tid >> 2,          p0 = (tid & 3) * 8;
  const int r1 = (tid + 256) >> 2,  p1 = p0;   // (tid+256)&3 == tid&3

  for (int k0 = 0; k0 < K; k0 += 32) {
    __syncthreads();
    const uint4 a0 = *(const uint4*)(A  + (size_t)(m0 + r0) * K + k0 + p0);
    const uint4 a1 = *(const uint4*)(A  + (size_t)(m0 + r1) * K + k0 + p1);
    const uint4 b0 = *(const uint4*)(Bt + (size_t)(n0 + r0) * K + k0 + p0);
    const uint4 b1 = *(const uint4*)(Bt + (size_t)(n0 + r1) * K + k0 + p1);
    *(uint4*)&As[r0][p0] = a0;
    *(uint4*)&As[r1][p1] = a1;
    *(uint4*)&Bs[r0][p0] = b0;
    *(uint4*)&Bs[r1][p1] = b1;
    __syncthreads();
    bf16x8 af[4], bfr[4];
    #pragma unroll
    for (int mt = 0; mt < 4; mt++) af[mt]  = *(const bf16x8*)&As[wr*64 + mt*16 + lrow][quad*8];
    #pragma unroll
    for (int nt = 0; nt < 4; nt++) bfr[nt] = *(const bf16x8*)&Bs[wc*64 + nt*16 + lrow][quad*8];
    #pragma unroll
    for (int mt = 0; mt < 4; mt++)
      #pragma unroll
      for (int nt = 0; nt < 4; nt++)
        acc[mt][nt] = __builtin_amdgcn_mfma_f32_16x16x32_bf16(af[mt], bfr[nt], acc[mt][nt], 0, 0, 0);
  }

  #pragma unroll
  for (int mt = 0; mt < 4; mt++) {
    #pragma unroll
    for (int nt = 0; nt < 4; nt++) {
      const int col = n0 + wc*64 + nt*16 + lrow;
      float bv = 0.f;
      if (BIAS) bv = bias[col];
      #pragma unroll
      for (int i = 0; i < 4; i++) {
        const int row = m0 + wr*64 + mt*16 + quad*4 + i;
        float vv = acc[mt][nt][i] + bv;
        if (RESID) vv += resid[(size_t)row * N + col];
        if (RELU)  vv = vv > 0.f ? vv : 0.f;
        if (OUTBF) ((bf16*)Cout)[(size_t)row * N + col] = (bf16)vv;
        else       ((float*)Cout)[(size_t)row * N + col] = vv;
      }
    }
  }
}

template<bool BIAS, bool RESID, bool RELU, bool OUTBF>
__global__ __launch_bounds__(256) void gemm_kernel(const bf16* __restrict__ A, const bf16* __restrict__ Bt,
    const float* __restrict__ bias, const float* __restrict__ resid, void* __restrict__ C, int N, int K) {
  gemm_core<BIAS, RESID, RELU, OUTBF>(A, Bt, bias, resid, C, N, K, blockIdx.x * 128, blockIdx.y * 128);
}

__global__ __launch_bounds__(256) void gemm_qkv_kernel(const bf16* __restrict__ A, const bf16* __restrict__ Wt,
    float* __restrict__ q, float* __restrict__ k, float* __restrict__ v) {
  const bf16* Bt = Wt + (size_t)blockIdx.z * (D_ * D_);
  float* C = blockIdx.z == 0 ? q : (blockIdx.z == 1 ? k : v);
  gemm_core<false, false, false, false>(A, Bt, nullptr, nullptr, C, D_, D_, blockIdx.x * 128, blockIdx.y * 128);
}

// ---------------- attention: per (b,h), thread-per-query-row, online softmax ----------------
__global__ __launch_bounds__(128) void attn_kernel(const float* __restrict__ q,
    const float* __restrict__ k, const float* __restrict__ v, bf16* __restrict__ attnb) {
  __shared__ float ks[T_][52];   // 52 floats = 208B row: 16B-aligned float4 writes
  __shared__ float vs[T_][52];
  const int bh = blockIdx.x;
  const int b = bh >> 3, h = bh & 7;
  const int r = threadIdx.x;     // 0..127 query row
  const size_t rowbase = ((size_t)(b * T_ + r)) * D_ + h * HS_;
  #pragma unroll
  for (int j = 0; j < 12; j++) {
    *(float4*)&ks[r][4*j] = *(const float4*)(k + rowbase + 4*j);
    *(float4*)&vs[r][4*j] = *(const float4*)(v + rowbase + 4*j);
  }
  float qr[48];
  #pragma unroll
  for (int j = 0; j < 12; j++) {
    const float4 t = *(const float4*)(q + rowbase + 4*j);
    qr[4*j] = t.x; qr[4*j+1] = t.y; qr[4*j+2] = t.z; qr[4*j+3] = t.w;
  }
  __syncthreads();
  float m = -3.0e38f, l = 0.f, acc[48];
  #pragma unroll
  for (int j = 0; j < 48; j++) acc[j] = 0.f;
  const float scale = 0.14433756729740643f;   // 48^-0.5
  for (int c = 0; c < T_; c++) {
    float s0 = 0.f, s1 = 0.f, s2 = 0.f, s3 = 0.f;
    #pragma unroll
    for (int j = 0; j < 48; j += 4) {
      s0 += qr[j]   * ks[c][j];
      s1 += qr[j+1] * ks[c][j+1];
      s2 += qr[j+2] * ks[c][j+2];
      s3 += qr[j+3] * ks[c][j+3];
    }
    float s = ((s0 + s1) + (s2 + s3)) * scale;
    if (c > r) s = -3.0e38f;                    // causal mask
    const float mn = fmaxf(m, s);
    const float al = __expf(m - mn);
    const float pp = __expf(s - mn);
    l = l * al + pp;
    #pragma unroll
    for (int j = 0; j < 48; j++) acc[j] = acc[j] * al + pp * vs[c][j];
    m = mn;
  }
  const float inv = 1.f / l;
  unsigned ob[24];
  #pragma unroll
  for (int j = 0; j < 24; j++)
    ob[j] = (unsigned)bfbits(acc[2*j] * inv) | ((unsigned)bfbits(acc[2*j+1] * inv) << 16);
  bf16* dst = attnb + rowbase;
  #pragma unroll
  for (int j = 0; j < 6; j++) {
    uint4 u; u.x = ob[4*j]; u.y = ob[4*j+1]; u.z = ob[4*j+2]; u.w = ob[4*j+3];
    *(uint4*)(dst + 8*j) = u;
  }
}

// ---------------- LayerNorm: one wave per row, D=384 = 64 lanes x 6 ----------------
__global__ __launch_bounds__(256) void ln_kernel(const float* __restrict__ in,
    const float* __restrict__ g, const float* __restrict__ bta,
    float* __restrict__ xo, bf16* __restrict__ xbo) {
  const int wave = threadIdx.x >> 6, lane = threadIdx.x & 63;
  const int row = blockIdx.x * 4 + wave;
  const float* p = in + (size_t)row * D_;
  float v[6];
  #pragma unroll
  for (int j = 0; j < 6; j++) v[j] = p[lane + 64*j];
  float s = 0.f;
  #pragma unroll
  for (int j = 0; j < 6; j++) s += v[j];
  s = waveReduceSum(s);
  const float mean = s * (1.f / 384.f);
  float qv = 0.f;
  #pragma unroll
  for (int j = 0; j < 6; j++) { v[j] -= mean; qv += v[j] * v[j]; }
  qv = waveReduceSum(qv);
  const float rs = rsqrtf(qv * (1.f / 384.f) + 1e-5f);
  #pragma unroll
  for (int j = 0; j < 6; j++) {
    const int c = lane + 64*j;
    const float o = v[j] * rs * g[c] + bta[c];
    xo[(size_t)row * D_ + c]  = o;
    xbo[(size_t)row * D_ + c] = (bf16)o;
  }
}

// ---------------- driver ----------------
extern "C" void kernel_launch(void* const* d_in, const int* in_sizes, int n_in,
                              void* d_out, int out_size, void* d_ws, size_t ws_size,
                              hipStream_t stream) {
  const int*   index = (const int*)  d_in[0];
  const float* tok   = (const float*)d_in[1];
  const float* pos   = (const float*)d_in[2];
  const float* Wq    = (const float*)d_in[3];
  const float* Wk    = (const float*)d_in[4];
  const float* Wv    = (const float*)d_in[5];
  const float* Wo    = (const float*)d_in[6];
  const float* bo    = (const float*)d_in[7];
  const float* W1    = (const float*)d_in[8];
  const float* b1    = (const float*)d_in[9];
  const float* W2    = (const float*)d_in[10];
  const float* b2    = (const float*)d_in[11];
  const float* ln1g  = (const float*)d_in[12];
  const float* ln1b  = (const float*)d_in[13];
  const float* ln2g  = (const float*)d_in[14];
  const float* ln2b  = (const float*)d_in[15];
  const float* lnfg  = (const float*)d_in[16];
  const float* lnfb  = (const float*)d_in[17];
  const float* lmW   = (const float*)d_in[18];
  const float* lmb   = (const float*)d_in[19];
  float* out = (float*)d_out;
  char* ws = (char*)d_ws;

  // ws layout (48 MB total). Transposed weights live in DEAD regions (lifetimes checked):
  float* x     = (float*)(ws + 0);          // 6.29 MB fp32 residual stream
  float* tmp   = (float*)(ws + 6291456);    // 6.29 MB fp32 pre-LN sums
  bf16*  xb    = (bf16*) (ws + 12582912);   // 3.15 MB bf16 copy of x
  float* qbuf  = (float*)(ws + 15728640);   // 6.29 MB
  float* kbuf  = (float*)(ws + 22020096);   // 6.29 MB
  float* vbuf  = (float*)(ws + 28311552);   // 6.29 MB
  bf16*  attnb = (bf16*) (ws + 34603008);   // 3.15 MB bf16 attention output
  bf16*  hb    = (bf16*) (ws + 37748736);   // 12.58 MB bf16 FFN hidden
  // aliases into dead regions:
  bf16* wqkvoT = (bf16*)(ws + 37748736);            // hb region (dead until gemm1): 4x 384x384
  bf16* w1t    = (bf16*)(ws + 34603008);            // attnb region (dead after Wo gemm)
  bf16* w2t    = (bf16*)(ws + 34603008 + 1179648);
  bf16* lmT    = (bf16*)(ws + 15728640);            // q..hb span (all dead at head time)

  embed_kernel<<<1536, 256, 0, stream>>>(index, tok, pos, x, xb);
  for (int l = 0; l < L_; l++) {
    t_qkvo_kernel<<<dim3(12, 12, 4), 256, 0, stream>>>(
        Wq + (size_t)l * D_ * D_, Wk + (size_t)l * D_ * D_,
        Wv + (size_t)l * D_ * D_, Wo + (size_t)l * D_ * D_, wqkvoT);
    gemm_qkv_kernel<<<dim3(32, 3, 3), 256, 0, stream>>>(xb, wqkvoT, qbuf, kbuf, vbuf);
    attn_kernel<<<256, 128, 0, stream>>>(qbuf, kbuf, vbuf, attnb);
    gemm_kernel<true, true, false, false><<<dim3(32, 3), 256, 0, stream>>>(
        attnb, wqkvoT + 3 * D_ * D_, bo + l * D_, x, tmp, D_, D_);
    ln_kernel<<<1024, 256, 0, stream>>>(tmp, ln1g + l * D_, ln1b + l * D_, x, xb);
    t_ffn_kernel<<<dim3(48, 48, 2), 256, 0, stream>>>(
        W1 + (size_t)l * D_ * 4 * D_, W2 + (size_t)l * 4 * D_ * D_, w1t, w2t);
    gemm_kernel<true, false, true, true><<<dim3(32, 12), 256, 0, stream>>>(
        xb, w1t, b1 + l * 4 * D_, nullptr, hb, 4 * D_, D_);
    gemm_kernel<true, true, false, false><<<dim3(32, 3), 256, 0, stream>>>(
        hb, w2t, b2 + l * D_, x, tmp, D_, 4 * D_);
    ln_kernel<<<1024, 256, 0, stream>>>(tmp, ln2g + l * D_, ln2b + l * D_, x, xb);
  }
  ln_kernel<<<1024, 256, 0, stream>>>(x, lnfg, lnfb, x, xb);
  t_head_kernel<<<dim3(1000, 12), 256, 0, stream>>>(lmW, lmT);
  gemm_kernel<true, false, false, false><<<dim3(32, 250), 256, 0, stream>>>(
      xb, lmT, lmb, nullptr, out, V_, D_);
}